// Round 1
// baseline (2216.808 us; speedup 1.0000x reference)
//
#include <hip/hip_runtime.h>
#include <hip/hip_bf16.h>

#define N_NODES 50000
#define N_EDGES 600000
#define D_IN    128
#define D_HID   1024
#define D_OUT   128

// ---------------------------------------------------------------------------
// Kernel 1: edge scatter.  thread = (edge, 4-float chunk).
// h[dst[e]] += feat[src[e]] + edge_feat[e]
// ---------------------------------------------------------------------------
__global__ __launch_bounds__(256) void scatter_kernel(
    const float* __restrict__ feat,
    const float* __restrict__ edge_feat,
    const int*   __restrict__ src,
    const int*   __restrict__ dst,
    float*       __restrict__ h)
{
    long i = (long)blockIdx.x * blockDim.x + threadIdx.x;   // over E * 32 float4 units
    const long total = (long)N_EDGES * (D_IN / 4);
    if (i >= total) return;
    int e  = (int)(i >> 5);        // i / 32
    int c4 = (int)(i & 31);        // float4 index within row
    int s = src[e];
    int d = dst[e];
    float4 ef = ((const float4*)edge_feat)[i];                        // e*32 + c4
    float4 fv = ((const float4*)(feat + (size_t)s * D_IN))[c4];
    float* hp = h + (size_t)d * D_IN + c4 * 4;
    atomicAdd(hp + 0, ef.x + fv.x);
    atomicAdd(hp + 1, ef.y + fv.y);
    atomicAdd(hp + 2, ef.z + fv.z);
    atomicAdd(hp + 3, ef.w + fv.w);
}

// ---------------------------------------------------------------------------
// Kernel 2: fused 2-layer MLP.
// Per block: 64 nodes. h_tile (64x128) in LDS. Hidden processed in chunks of
// 64 units through LDS; W1/W2 stream from L2 (each 512 KB, L2-resident).
// Thread layout: t -> row group g = t/32 (8 rows each), lane = t%32.
//   layer1: thread computes hid[g*8 .. g*8+7][lane*2, lane*2+1]
//   layer2: thread accumulates out[g*8 .. g*8+7][lane*4 .. lane*4+3]
// ---------------------------------------------------------------------------
#define TN 64
#define TJ 64

__global__ __launch_bounds__(256) void mlp_kernel(
    const float* __restrict__ h,     // [N, 128]
    const float* __restrict__ W1,    // [128, 1024]
    const float* __restrict__ b1,    // [1024]
    const float* __restrict__ W2,    // [1024, 128]
    const float* __restrict__ b2,    // [128]
    float*       __restrict__ out)   // [N, 128]
{
    __shared__ float h_s[TN][D_IN];        // 32 KB
    __shared__ float hid_s[TN][TJ + 4];    // 17 KB, +4 pad keeps 16B alignment

    const int t  = threadIdx.x;
    const int nb = blockIdx.x * TN;

    // ---- load h tile (zero-fill rows past N_NODES) ----
    for (int i = t; i < TN * D_IN / 4; i += 256) {
        int row  = i >> 5;          // 32 float4 per row
        int col4 = i & 31;
        float4 v = make_float4(0.f, 0.f, 0.f, 0.f);
        if (nb + row < N_NODES)
            v = ((const float4*)(h + (size_t)(nb + row) * D_IN))[col4];
        ((float4*)&h_s[row][0])[col4] = v;
    }
    __syncthreads();

    const int g    = t >> 5;        // row group 0..7
    const int lane = t & 31;
    const int jc   = lane * 2;      // layer-1 hidden cols
    const int c4   = lane * 4;      // layer-2 out cols

    float acc[8][4];
    #pragma unroll
    for (int r = 0; r < 8; ++r)
        #pragma unroll
        for (int q = 0; q < 4; ++q) acc[r][q] = 0.f;

    for (int jb = 0; jb < D_HID; jb += TJ) {
        // ---- layer 1: hid chunk [64][TJ] ----
        float s0[8], s1[8];
        {
            float bb0 = b1[jb + jc];
            float bb1 = b1[jb + jc + 1];
            #pragma unroll
            for (int r = 0; r < 8; ++r) { s0[r] = bb0; s1[r] = bb1; }
        }
        #pragma unroll 2
        for (int k = 0; k < D_IN; k += 4) {
            float2 w0 = *(const float2*)(W1 + (size_t)(k + 0) * D_HID + jb + jc);
            float2 w1 = *(const float2*)(W1 + (size_t)(k + 1) * D_HID + jb + jc);
            float2 w2 = *(const float2*)(W1 + (size_t)(k + 2) * D_HID + jb + jc);
            float2 w3 = *(const float2*)(W1 + (size_t)(k + 3) * D_HID + jb + jc);
            #pragma unroll
            for (int r = 0; r < 8; ++r) {
                float4 hv = *(const float4*)&h_s[g * 8 + r][k];
                s0[r] += hv.x * w0.x + hv.y * w1.x + hv.z * w2.x + hv.w * w3.x;
                s1[r] += hv.x * w0.y + hv.y * w1.y + hv.z * w2.y + hv.w * w3.y;
            }
        }
        __syncthreads();   // previous chunk's layer-2 reads done before overwrite
        #pragma unroll
        for (int r = 0; r < 8; ++r) {
            hid_s[g * 8 + r][jc]     = fmaxf(s0[r], 0.f);
            hid_s[g * 8 + r][jc + 1] = fmaxf(s1[r], 0.f);
        }
        __syncthreads();

        // ---- layer 2: out += hid_chunk @ W2[jb:jb+TJ, :] ----
        #pragma unroll 2
        for (int jj = 0; jj < TJ; jj += 4) {
            float4 w0 = *(const float4*)(W2 + (size_t)(jb + jj + 0) * D_OUT + c4);
            float4 w1 = *(const float4*)(W2 + (size_t)(jb + jj + 1) * D_OUT + c4);
            float4 w2 = *(const float4*)(W2 + (size_t)(jb + jj + 2) * D_OUT + c4);
            float4 w3 = *(const float4*)(W2 + (size_t)(jb + jj + 3) * D_OUT + c4);
            #pragma unroll
            for (int r = 0; r < 8; ++r) {
                float4 hv = *(const float4*)&hid_s[g * 8 + r][jj];
                acc[r][0] += hv.x * w0.x + hv.y * w1.x + hv.z * w2.x + hv.w * w3.x;
                acc[r][1] += hv.x * w0.y + hv.y * w1.y + hv.z * w2.y + hv.w * w3.y;
                acc[r][2] += hv.x * w0.z + hv.y * w1.z + hv.z * w2.z + hv.w * w3.z;
                acc[r][3] += hv.x * w0.w + hv.y * w1.w + hv.z * w2.w + hv.w * w3.w;
            }
        }
    }

    // ---- epilogue: add b2, store ----
    float4 bias = *(const float4*)(b2 + c4);
    #pragma unroll
    for (int r = 0; r < 8; ++r) {
        int row = nb + g * 8 + r;
        if (row < N_NODES) {
            float4 o;
            o.x = acc[r][0] + bias.x;
            o.y = acc[r][1] + bias.y;
            o.z = acc[r][2] + bias.z;
            o.w = acc[r][3] + bias.w;
            ((float4*)(out + (size_t)row * D_OUT))[lane] = o;
        }
    }
}

// ---------------------------------------------------------------------------
extern "C" void kernel_launch(void* const* d_in, const int* in_sizes, int n_in,
                              void* d_out, int out_size, void* d_ws, size_t ws_size,
                              hipStream_t stream) {
    const float* feat      = (const float*)d_in[0];
    const float* edge_feat = (const float*)d_in[1];
    const int*   src       = (const int*)d_in[2];
    const int*   dst       = (const int*)d_in[3];
    const float* W1        = (const float*)d_in[4];
    const float* b1        = (const float*)d_in[5];
    const float* W2        = (const float*)d_in[6];
    const float* b2        = (const float*)d_in[7];
    float* out = (float*)d_out;

    float* h = (float*)d_ws;   // [N_NODES, D_IN] fp32 accumulator = 25.6 MB

    // zero accumulator (ws is re-poisoned to 0xAA before every timed launch)
    hipMemsetAsync(h, 0, (size_t)N_NODES * D_IN * sizeof(float), stream);

    // scatter
    {
        long total = (long)N_EDGES * (D_IN / 4);
        int blocks = (int)((total + 255) / 256);
        scatter_kernel<<<blocks, 256, 0, stream>>>(feat, edge_feat, src, dst, h);
    }

    // fused MLP
    {
        int blocks = (N_NODES + TN - 1) / TN;   // 782
        mlp_kernel<<<blocks, 256, 0, stream>>>(h, W1, b1, W2, b2, out);
    }
}

// Round 2
// 1492.705 us; speedup vs baseline: 1.4851x; 1.4851x over previous
//
#include <hip/hip_runtime.h>
#include <hip/hip_bf16.h>

#define N_NODES 50000
#define N_EDGES 600000
#define D_IN    128
#define D_HID   1024
#define D_OUT   128

// ---------------------------------------------------------------------------
// Workspace layout (bytes):
//   h      : [N_NODES * D_IN] float   @ 0            (25,600,000 B)
//   eid    : [N_EDGES] int            @ 25,600,000   ( 2,400,000 B)
//   off    : [N_NODES+1] int          @ 28,000,000   (   200,016 B padded)
//   cursor : [N_NODES] int            @ 28,200,016   (   200,000 B)
//   deg    : [N_NODES] int            @ 28,400,016   (   200,000 B)
// ---------------------------------------------------------------------------
#define WS_H      0
#define WS_EID    25600000
#define WS_OFF    28000000
#define WS_CURSOR 28200016
#define WS_DEG    28400016

// ---------------------------------------------------------------------------
// CSR build step 1: histogram of dst
// ---------------------------------------------------------------------------
__global__ __launch_bounds__(256) void hist_kernel(
    const int* __restrict__ dst, int* __restrict__ deg)
{
    int e = blockIdx.x * blockDim.x + threadIdx.x;
    if (e < N_EDGES) atomicAdd(&deg[dst[e]], 1);
}

// ---------------------------------------------------------------------------
// CSR build step 2: exclusive prefix scan over deg (single block).
// Each thread serially scans a 49-element chunk; block-scan of chunk totals.
// Writes off[] (exclusive offsets), cursor[] (= off copy), off[N_NODES]=E.
// ---------------------------------------------------------------------------
__global__ __launch_bounds__(1024) void scan_kernel(
    const int* __restrict__ deg, int* __restrict__ off, int* __restrict__ cursor)
{
    __shared__ int part[1024];
    const int t = threadIdx.x;
    const int CH = 49;                      // 1024*49 = 50176 >= 50000
    const int base = t * CH;

    int s = 0;
    for (int i = 0; i < CH; ++i) {
        int idx = base + i;
        if (idx < N_NODES) s += deg[idx];
    }
    part[t] = s;
    __syncthreads();
    // Hillis-Steele inclusive scan
    for (int ofs = 1; ofs < 1024; ofs <<= 1) {
        int v = (t >= ofs) ? part[t - ofs] : 0;
        __syncthreads();
        part[t] += v;
        __syncthreads();
    }
    int run = (t == 0) ? 0 : part[t - 1];   // exclusive prefix of this chunk
    for (int i = 0; i < CH; ++i) {
        int idx = base + i;
        if (idx < N_NODES) {
            off[idx] = run;
            cursor[idx] = run;
            run += deg[idx];
        }
    }
    if (t == 1023) off[N_NODES] = part[1023];   // total = N_EDGES
}

// ---------------------------------------------------------------------------
// CSR build step 3: drop edge ids into their dst bucket
// ---------------------------------------------------------------------------
__global__ __launch_bounds__(256) void fill_kernel(
    const int* __restrict__ dst, int* __restrict__ cursor, int* __restrict__ eid)
{
    int e = blockIdx.x * blockDim.x + threadIdx.x;
    if (e < N_EDGES) {
        int pos = atomicAdd(&cursor[dst[e]], 1);
        eid[pos] = e;
    }
}

// ---------------------------------------------------------------------------
// Gather: one wave per node. Lane l holds float2 (cols 2l, 2l+1).
// h[n] = sum_{e in in(n)} (feat[src[e]] + edge_feat[e]);  no atomics.
// 2-edge unroll for two independent load chains per wave.
// ---------------------------------------------------------------------------
__global__ __launch_bounds__(256) void gather_kernel(
    const float* __restrict__ feat,
    const float* __restrict__ edge_feat,
    const int*   __restrict__ src,
    const int*   __restrict__ eid,
    const int*   __restrict__ off,
    float*       __restrict__ h)
{
    const int wave = threadIdx.x >> 6;
    const int lane = threadIdx.x & 63;
    const int n = blockIdx.x * 4 + wave;
    if (n >= N_NODES) return;

    int i   = off[n];
    int end = off[n + 1];

    float2 acc0 = make_float2(0.f, 0.f);
    float2 acc1 = make_float2(0.f, 0.f);

    for (; i + 1 < end; i += 2) {
        int e0 = eid[i], e1 = eid[i + 1];
        int s0 = src[e0], s1 = src[e1];
        float2 a0 = ((const float2*)(edge_feat + (size_t)e0 * D_IN))[lane];
        float2 b0 = ((const float2*)(feat      + (size_t)s0 * D_IN))[lane];
        float2 a1 = ((const float2*)(edge_feat + (size_t)e1 * D_IN))[lane];
        float2 b1 = ((const float2*)(feat      + (size_t)s1 * D_IN))[lane];
        acc0.x += a0.x + b0.x;  acc0.y += a0.y + b0.y;
        acc1.x += a1.x + b1.x;  acc1.y += a1.y + b1.y;
    }
    if (i < end) {
        int e0 = eid[i];
        int s0 = src[e0];
        float2 a0 = ((const float2*)(edge_feat + (size_t)e0 * D_IN))[lane];
        float2 b0 = ((const float2*)(feat      + (size_t)s0 * D_IN))[lane];
        acc0.x += a0.x + b0.x;  acc0.y += a0.y + b0.y;
    }
    float2 r = make_float2(acc0.x + acc1.x, acc0.y + acc1.y);
    ((float2*)(h + (size_t)n * D_IN))[lane] = r;
}

// ---------------------------------------------------------------------------
// Fused 2-layer MLP (unchanged from R1).
// ---------------------------------------------------------------------------
#define TN 64
#define TJ 64

__global__ __launch_bounds__(256) void mlp_kernel(
    const float* __restrict__ h,     // [N, 128]
    const float* __restrict__ W1,    // [128, 1024]
    const float* __restrict__ b1,    // [1024]
    const float* __restrict__ W2,    // [1024, 128]
    const float* __restrict__ b2,    // [128]
    float*       __restrict__ out)   // [N, 128]
{
    __shared__ float h_s[TN][D_IN];        // 32 KB
    __shared__ float hid_s[TN][TJ + 4];    // 17 KB

    const int t  = threadIdx.x;
    const int nb = blockIdx.x * TN;

    for (int i = t; i < TN * D_IN / 4; i += 256) {
        int row  = i >> 5;
        int col4 = i & 31;
        float4 v = make_float4(0.f, 0.f, 0.f, 0.f);
        if (nb + row < N_NODES)
            v = ((const float4*)(h + (size_t)(nb + row) * D_IN))[col4];
        ((float4*)&h_s[row][0])[col4] = v;
    }
    __syncthreads();

    const int g    = t >> 5;
    const int lane = t & 31;
    const int jc   = lane * 2;
    const int c4   = lane * 4;

    float acc[8][4];
    #pragma unroll
    for (int r = 0; r < 8; ++r)
        #pragma unroll
        for (int q = 0; q < 4; ++q) acc[r][q] = 0.f;

    for (int jb = 0; jb < D_HID; jb += TJ) {
        float s0[8], s1[8];
        {
            float bb0 = b1[jb + jc];
            float bb1 = b1[jb + jc + 1];
            #pragma unroll
            for (int r = 0; r < 8; ++r) { s0[r] = bb0; s1[r] = bb1; }
        }
        #pragma unroll 2
        for (int k = 0; k < D_IN; k += 4) {
            float2 w0 = *(const float2*)(W1 + (size_t)(k + 0) * D_HID + jb + jc);
            float2 w1 = *(const float2*)(W1 + (size_t)(k + 1) * D_HID + jb + jc);
            float2 w2 = *(const float2*)(W1 + (size_t)(k + 2) * D_HID + jb + jc);
            float2 w3 = *(const float2*)(W1 + (size_t)(k + 3) * D_HID + jb + jc);
            #pragma unroll
            for (int r = 0; r < 8; ++r) {
                float4 hv = *(const float4*)&h_s[g * 8 + r][k];
                s0[r] += hv.x * w0.x + hv.y * w1.x + hv.z * w2.x + hv.w * w3.x;
                s1[r] += hv.x * w0.y + hv.y * w1.y + hv.z * w2.y + hv.w * w3.y;
            }
        }
        __syncthreads();
        #pragma unroll
        for (int r = 0; r < 8; ++r) {
            hid_s[g * 8 + r][jc]     = fmaxf(s0[r], 0.f);
            hid_s[g * 8 + r][jc + 1] = fmaxf(s1[r], 0.f);
        }
        __syncthreads();

        #pragma unroll 2
        for (int jj = 0; jj < TJ; jj += 4) {
            float4 w0 = *(const float4*)(W2 + (size_t)(jb + jj + 0) * D_OUT + c4);
            float4 w1 = *(const float4*)(W2 + (size_t)(jb + jj + 1) * D_OUT + c4);
            float4 w2 = *(const float4*)(W2 + (size_t)(jb + jj + 2) * D_OUT + c4);
            float4 w3 = *(const float4*)(W2 + (size_t)(jb + jj + 3) * D_OUT + c4);
            #pragma unroll
            for (int r = 0; r < 8; ++r) {
                float4 hv = *(const float4*)&hid_s[g * 8 + r][jj];
                acc[r][0] += hv.x * w0.x + hv.y * w1.x + hv.z * w2.x + hv.w * w3.x;
                acc[r][1] += hv.x * w0.y + hv.y * w1.y + hv.z * w2.y + hv.w * w3.y;
                acc[r][2] += hv.x * w0.z + hv.y * w1.z + hv.z * w2.z + hv.w * w3.z;
                acc[r][3] += hv.x * w0.w + hv.y * w1.w + hv.z * w2.w + hv.w * w3.w;
            }
        }
    }

    float4 bias = *(const float4*)(b2 + c4);
    #pragma unroll
    for (int r = 0; r < 8; ++r) {
        int row = nb + g * 8 + r;
        if (row < N_NODES) {
            float4 o;
            o.x = acc[r][0] + bias.x;
            o.y = acc[r][1] + bias.y;
            o.z = acc[r][2] + bias.z;
            o.w = acc[r][3] + bias.w;
            ((float4*)(out + (size_t)row * D_OUT))[lane] = o;
        }
    }
}

// ---------------------------------------------------------------------------
extern "C" void kernel_launch(void* const* d_in, const int* in_sizes, int n_in,
                              void* d_out, int out_size, void* d_ws, size_t ws_size,
                              hipStream_t stream) {
    const float* feat      = (const float*)d_in[0];
    const float* edge_feat = (const float*)d_in[1];
    const int*   src       = (const int*)d_in[2];
    const int*   dst       = (const int*)d_in[3];
    const float* W1        = (const float*)d_in[4];
    const float* b1        = (const float*)d_in[5];
    const float* W2        = (const float*)d_in[6];
    const float* b2        = (const float*)d_in[7];
    float* out = (float*)d_out;

    char* ws = (char*)d_ws;
    float* h      = (float*)(ws + WS_H);
    int*   eid    = (int*)(ws + WS_EID);
    int*   off    = (int*)(ws + WS_OFF);
    int*   cursor = (int*)(ws + WS_CURSOR);
    int*   deg    = (int*)(ws + WS_DEG);

    // zero the degree counters (ws is poisoned to 0xAA before every launch)
    hipMemsetAsync(deg, 0, (size_t)N_NODES * sizeof(int), stream);

    // CSR build
    hist_kernel<<<(N_EDGES + 255) / 256, 256, 0, stream>>>(dst, deg);
    scan_kernel<<<1, 1024, 0, stream>>>(deg, off, cursor);
    fill_kernel<<<(N_EDGES + 255) / 256, 256, 0, stream>>>(dst, cursor, eid);

    // gather (atomic-free): one wave per node, 4 nodes per block
    gather_kernel<<<(N_NODES + 3) / 4, 256, 0, stream>>>(feat, edge_feat, src, eid, off, h);

    // fused MLP
    mlp_kernel<<<(N_NODES + TN - 1) / TN, 256, 0, stream>>>(h, W1, b1, W2, b2, out);
}

// Round 3
// 612.918 us; speedup vs baseline: 3.6168x; 2.4354x over previous
//
#include <hip/hip_runtime.h>
#include <hip/hip_bf16.h>

#define N_NODES 50000
#define N_EDGES 600000
#define D_IN    128
#define D_HID   1024
#define D_OUT   128

// ---------------------------------------------------------------------------
// Workspace layout (bytes):
//   hbf    : [N_NODES*128] bf16   @ 0            (12,800,000)
//   eid    : [N_EDGES] int        @ 12,800,000   ( 2,400,000)
//   off    : [N_NODES+1] int      @ 15,200,000   (   200,016)
//   cursor : [N_NODES] int        @ 15,400,016   (   200,000)
//   deg    : [N_NODES] int        @ 15,600,016   (   200,000)
//   bsum   : [256] int            @ 15,800,016   (     1,024)
//   W1T    : [1024*128] bf16      @ 15,801,040   (   262,144)   [n][k]
//   W2T    : [128*1024] bf16      @ 16,063,184   (   262,144)   [n][k]
// ---------------------------------------------------------------------------
#define WS_H      0
#define WS_EID    12800000
#define WS_OFF    15200000
#define WS_CURSOR 15400016
#define WS_DEG    15600016
#define WS_BSUM   15800016
#define WS_W1T    15801040
#define WS_W2T    16063184

typedef short bf16x8 __attribute__((ext_vector_type(8)));
typedef float f32x4  __attribute__((ext_vector_type(4)));

// ---------------------------------------------------------------------------
// CSR step 1: histogram of dst
// ---------------------------------------------------------------------------
__global__ __launch_bounds__(256) void hist_kernel(
    const int* __restrict__ dst, int* __restrict__ deg)
{
    int e = blockIdx.x * blockDim.x + threadIdx.x;
    if (e < N_EDGES) atomicAdd(&deg[dst[e]], 1);
}

// ---------------------------------------------------------------------------
// CSR step 2a: per-block sums of deg (coalesced). 196 blocks x 256.
// ---------------------------------------------------------------------------
__global__ __launch_bounds__(256) void scan1_kernel(
    const int* __restrict__ deg, int* __restrict__ bsum)
{
    __shared__ int red[256];
    int t = threadIdx.x;
    int idx = blockIdx.x * 256 + t;
    red[t] = (idx < N_NODES) ? deg[idx] : 0;
    __syncthreads();
    for (int s = 128; s > 0; s >>= 1) {
        if (t < s) red[t] += red[t + s];
        __syncthreads();
    }
    if (t == 0) bsum[blockIdx.x] = red[0];
}

// ---------------------------------------------------------------------------
// CSR step 2b: exclusive scan of 196 block sums (single small block).
// Also writes off[N_NODES] = total.
// ---------------------------------------------------------------------------
#define SCAN_NB 196
__global__ __launch_bounds__(256) void scan2_kernel(
    int* __restrict__ bsum, int* __restrict__ off)
{
    __shared__ int sh[256];
    int t = threadIdx.x;
    int v = (t < SCAN_NB) ? bsum[t] : 0;
    sh[t] = v;
    __syncthreads();
    for (int ofs = 1; ofs < 256; ofs <<= 1) {
        int u = (t >= ofs) ? sh[t - ofs] : 0;
        __syncthreads();
        sh[t] += u;
        __syncthreads();
    }
    if (t < SCAN_NB) bsum[t] = sh[t] - v;       // exclusive
    if (t == 255) off[N_NODES] = sh[255];       // total == N_EDGES
}

// ---------------------------------------------------------------------------
// CSR step 2c: block-local scan + block offset -> off[], cursor[]
// ---------------------------------------------------------------------------
__global__ __launch_bounds__(256) void scan3_kernel(
    const int* __restrict__ deg, const int* __restrict__ bsum,
    int* __restrict__ off, int* __restrict__ cursor)
{
    __shared__ int sh[256];
    int t = threadIdx.x;
    int idx = blockIdx.x * 256 + t;
    int v = (idx < N_NODES) ? deg[idx] : 0;
    sh[t] = v;
    __syncthreads();
    for (int ofs = 1; ofs < 256; ofs <<= 1) {
        int u = (t >= ofs) ? sh[t - ofs] : 0;
        __syncthreads();
        sh[t] += u;
        __syncthreads();
    }
    if (idx < N_NODES) {
        int ex = bsum[blockIdx.x] + sh[t] - v;
        off[idx] = ex;
        cursor[idx] = ex;
    }
}

// ---------------------------------------------------------------------------
// CSR step 3: drop edge ids into dst buckets
// ---------------------------------------------------------------------------
__global__ __launch_bounds__(256) void fill_kernel(
    const int* __restrict__ dst, int* __restrict__ cursor, int* __restrict__ eid)
{
    int e = blockIdx.x * blockDim.x + threadIdx.x;
    if (e < N_EDGES) {
        int pos = atomicAdd(&cursor[dst[e]], 1);
        eid[pos] = e;
    }
}

// ---------------------------------------------------------------------------
// Transpose + fp32->bf16 convert: in[rows][cols] f32 -> out[cols][rows] bf16
// ---------------------------------------------------------------------------
__global__ __launch_bounds__(256) void transpose_cvt_kernel(
    const float* __restrict__ in, __hip_bfloat16* __restrict__ outp,
    int rows, int cols)
{
    __shared__ float tile[32][33];
    int c0 = blockIdx.x * 32, r0 = blockIdx.y * 32;
    int tx = threadIdx.x & 31, ty = threadIdx.x >> 5;   // ty 0..7
    #pragma unroll
    for (int i = 0; i < 32; i += 8) {
        int r = r0 + ty + i, c = c0 + tx;
        tile[ty + i][tx] = (r < rows && c < cols) ? in[(size_t)r * cols + c] : 0.f;
    }
    __syncthreads();
    #pragma unroll
    for (int i = 0; i < 32; i += 8) {
        int c = c0 + ty + i, r = r0 + tx;
        if (r < rows && c < cols)
            outp[(size_t)c * rows + r] = __float2bfloat16(tile[tx][ty + i]);
    }
}

// ---------------------------------------------------------------------------
// Gather: one wave per node; lane holds float2 (cols 2l,2l+1). Indices forced
// scalar; 4-edge unroll -> 4 independent 1KB load chains. Output bf16.
// ---------------------------------------------------------------------------
__global__ __launch_bounds__(256) void gather_kernel(
    const float* __restrict__ feat,
    const float* __restrict__ edge_feat,
    const int*   __restrict__ src,
    const int*   __restrict__ eid,
    const int*   __restrict__ off,
    __hip_bfloat16* __restrict__ hbf)
{
    const int wv   = __builtin_amdgcn_readfirstlane(threadIdx.x >> 6);
    const int lane = threadIdx.x & 63;
    const int n = blockIdx.x * 4 + wv;
    if (n >= N_NODES) return;

    int i   = __builtin_amdgcn_readfirstlane(off[n]);
    int end = __builtin_amdgcn_readfirstlane(off[n + 1]);

    float2 a0 = make_float2(0.f, 0.f), a1 = a0, a2 = a0, a3 = a0;

    for (; i + 3 < end; i += 4) {
        int e0 = __builtin_amdgcn_readfirstlane(eid[i]);
        int e1 = __builtin_amdgcn_readfirstlane(eid[i + 1]);
        int e2 = __builtin_amdgcn_readfirstlane(eid[i + 2]);
        int e3 = __builtin_amdgcn_readfirstlane(eid[i + 3]);
        int s0 = __builtin_amdgcn_readfirstlane(src[e0]);
        int s1 = __builtin_amdgcn_readfirstlane(src[e1]);
        int s2 = __builtin_amdgcn_readfirstlane(src[e2]);
        int s3 = __builtin_amdgcn_readfirstlane(src[e3]);
        float2 f0 = ((const float2*)(edge_feat + (size_t)e0 * D_IN))[lane];
        float2 g0 = ((const float2*)(feat      + (size_t)s0 * D_IN))[lane];
        float2 f1 = ((const float2*)(edge_feat + (size_t)e1 * D_IN))[lane];
        float2 g1 = ((const float2*)(feat      + (size_t)s1 * D_IN))[lane];
        float2 f2 = ((const float2*)(edge_feat + (size_t)e2 * D_IN))[lane];
        float2 g2 = ((const float2*)(feat      + (size_t)s2 * D_IN))[lane];
        float2 f3 = ((const float2*)(edge_feat + (size_t)e3 * D_IN))[lane];
        float2 g3 = ((const float2*)(feat      + (size_t)s3 * D_IN))[lane];
        a0.x += f0.x + g0.x;  a0.y += f0.y + g0.y;
        a1.x += f1.x + g1.x;  a1.y += f1.y + g1.y;
        a2.x += f2.x + g2.x;  a2.y += f2.y + g2.y;
        a3.x += f3.x + g3.x;  a3.y += f3.y + g3.y;
    }
    for (; i < end; ++i) {
        int e = __builtin_amdgcn_readfirstlane(eid[i]);
        int s = __builtin_amdgcn_readfirstlane(src[e]);
        float2 f = ((const float2*)(edge_feat + (size_t)e * D_IN))[lane];
        float2 g = ((const float2*)(feat      + (size_t)s * D_IN))[lane];
        a0.x += f.x + g.x;  a0.y += f.y + g.y;
    }
    float sx = (a0.x + a1.x) + (a2.x + a3.x);
    float sy = (a0.y + a1.y) + (a2.y + a3.y);
    __hip_bfloat162 hv;
    hv.x = __float2bfloat16(sx);
    hv.y = __float2bfloat16(sy);
    ((__hip_bfloat162*)(hbf + (size_t)n * D_IN))[lane] = hv;
}

// ---------------------------------------------------------------------------
// Fused MFMA MLP. 64 nodes/block, 4 waves.
// Layer1: wave w computes hid[:, jb + w*16 .. +16) -- A (h tile) held in regs,
//         B streamed from W1T[n][k] (contiguous 16B frags).
// Hidden chunk relu'd -> bf16 -> LDS (A-operand layout), then
// Layer2: wave w computes out[:, w*32 .. +32), K = chunk, B from W2T[n][k].
// ---------------------------------------------------------------------------
#define HS_STRIDE 136   // shorts per h_s row (272 B = 17*16, banks shift 4/row)
#define QS_STRIDE 72    // shorts per q_s row (144 B =  9*16)

__global__ __launch_bounds__(256) void mlp_mfma_kernel(
    const __hip_bfloat16* __restrict__ hbf,   // [N][128]
    const __hip_bfloat16* __restrict__ w1t,   // [1024][128]
    const float* __restrict__ b1,             // [1024]
    const __hip_bfloat16* __restrict__ w2t,   // [128][1024]
    const float* __restrict__ b2,             // [128]
    float* __restrict__ out)                  // [N][128]
{
    __shared__ __align__(16) short h_s[64 * HS_STRIDE];  // 17.4 KB
    __shared__ __align__(16) short q_s[64 * QS_STRIDE];  //  9.2 KB

    const int t    = threadIdx.x;
    const int wv   = t >> 6;
    const int lane = t & 63;
    const int half = lane >> 4;    // quad 0..3
    const int lid  = lane & 15;
    const int nb   = blockIdx.x * 64;

    const short* hs  = (const short*)hbf;
    const short* w1s = (const short*)w1t;
    const short* w2s = (const short*)w2t;

    // ---- stage h tile (64 rows x 256 B) ----
    for (int u = t; u < 64 * 16; u += 256) {
        int r = u >> 4, c = u & 15;
        int row = nb + r;
        uint4 v = make_uint4(0u, 0u, 0u, 0u);
        if (row < N_NODES) v = ((const uint4*)(hs + (size_t)row * 128))[c];
        *(uint4*)&h_s[r * HS_STRIDE + c * 8] = v;
    }
    __syncthreads();

    // ---- A fragments for layer 1 (held in registers for all chunks) ----
    bf16x8 afrag[4][4];
    #pragma unroll
    for (int mt = 0; mt < 4; ++mt)
        #pragma unroll
        for (int ks = 0; ks < 4; ++ks)
            afrag[mt][ks] = *(const bf16x8*)&h_s[(mt * 16 + lid) * HS_STRIDE + ks * 32 + half * 8];

    f32x4 acc[4][2];
    #pragma unroll
    for (int mt = 0; mt < 4; ++mt) {
        acc[mt][0] = f32x4{0.f, 0.f, 0.f, 0.f};
        acc[mt][1] = f32x4{0.f, 0.f, 0.f, 0.f};
    }

    const int ncol1 = wv * 16 + lid;   // within-chunk hidden column for layer-1 B

    for (int jb = 0; jb < D_HID; jb += 64) {
        // ---- layer 1 ----
        float bias = b1[jb + ncol1];
        bf16x8 bfrag[4];
        #pragma unroll
        for (int ks = 0; ks < 4; ++ks)
            bfrag[ks] = *(const bf16x8*)&w1s[(size_t)(jb + ncol1) * 128 + ks * 32 + half * 8];

        f32x4 c1[4];
        #pragma unroll
        for (int mt = 0; mt < 4; ++mt) {
            f32x4 c = f32x4{bias, bias, bias, bias};
            #pragma unroll
            for (int ks = 0; ks < 4; ++ks)
                c = __builtin_amdgcn_mfma_f32_16x16x32_bf16(afrag[mt][ks], bfrag[ks], c, 0, 0, 0);
            c1[mt] = c;
        }

        __syncthreads();   // previous chunk's layer-2 reads of q_s complete
        #pragma unroll
        for (int mt = 0; mt < 4; ++mt) {
            #pragma unroll
            for (int r = 0; r < 4; ++r) {
                float v = fmaxf(c1[mt][r], 0.f);
                __hip_bfloat16 bv = __float2bfloat16(v);
                q_s[(mt * 16 + half * 4 + r) * QS_STRIDE + wv * 16 + lid] = *(short*)&bv;
            }
        }
        __syncthreads();

        // ---- layer 2 ----
        bf16x8 a2f[4][2];
        #pragma unroll
        for (int mt = 0; mt < 4; ++mt)
            #pragma unroll
            for (int ks = 0; ks < 2; ++ks)
                a2f[mt][ks] = *(const bf16x8*)&q_s[(mt * 16 + lid) * QS_STRIDE + ks * 32 + half * 8];

        #pragma unroll
        for (int nt = 0; nt < 2; ++nt) {
            #pragma unroll
            for (int ks = 0; ks < 2; ++ks) {
                bf16x8 b2f = *(const bf16x8*)&w2s[(size_t)(wv * 32 + nt * 16 + lid) * 1024 + jb + ks * 32 + half * 8];
                #pragma unroll
                for (int mt = 0; mt < 4; ++mt)
                    acc[mt][nt] = __builtin_amdgcn_mfma_f32_16x16x32_bf16(a2f[mt][ks], b2f, acc[mt][nt], 0, 0, 0);
            }
        }
    }

    // ---- epilogue ----
    #pragma unroll
    for (int nt = 0; nt < 2; ++nt) {
        int col = wv * 32 + nt * 16 + lid;
        float bv = b2[col];
        #pragma unroll
        for (int mt = 0; mt < 4; ++mt) {
            #pragma unroll
            for (int r = 0; r < 4; ++r) {
                int row = nb + mt * 16 + half * 4 + r;
                if (row < N_NODES)
                    out[(size_t)row * D_OUT + col] = acc[mt][nt][r] + bv;
            }
        }
    }
}

// ---------------------------------------------------------------------------
extern "C" void kernel_launch(void* const* d_in, const int* in_sizes, int n_in,
                              void* d_out, int out_size, void* d_ws, size_t ws_size,
                              hipStream_t stream) {
    const float* feat      = (const float*)d_in[0];
    const float* edge_feat = (const float*)d_in[1];
    const int*   src       = (const int*)d_in[2];
    const int*   dst       = (const int*)d_in[3];
    const float* W1        = (const float*)d_in[4];
    const float* b1        = (const float*)d_in[5];
    const float* W2        = (const float*)d_in[6];
    const float* b2        = (const float*)d_in[7];
    float* out = (float*)d_out;

    char* ws = (char*)d_ws;
    __hip_bfloat16* hbf    = (__hip_bfloat16*)(ws + WS_H);
    int*   eid    = (int*)(ws + WS_EID);
    int*   off    = (int*)(ws + WS_OFF);
    int*   cursor = (int*)(ws + WS_CURSOR);
    int*   deg    = (int*)(ws + WS_DEG);
    int*   bsum   = (int*)(ws + WS_BSUM);
    __hip_bfloat16* w1t = (__hip_bfloat16*)(ws + WS_W1T);
    __hip_bfloat16* w2t = (__hip_bfloat16*)(ws + WS_W2T);

    hipMemsetAsync(deg, 0, (size_t)N_NODES * sizeof(int), stream);

    // CSR build
    hist_kernel<<<(N_EDGES + 255) / 256, 256, 0, stream>>>(dst, deg);
    scan1_kernel<<<SCAN_NB, 256, 0, stream>>>(deg, bsum);
    scan2_kernel<<<1, 256, 0, stream>>>(bsum, off);
    scan3_kernel<<<SCAN_NB, 256, 0, stream>>>(deg, bsum, off, cursor);
    fill_kernel<<<(N_EDGES + 255) / 256, 256, 0, stream>>>(dst, cursor, eid);

    // weight transpose + convert (W1[128][1024] -> W1T[1024][128]; W2 -> W2T)
    transpose_cvt_kernel<<<dim3(1024 / 32, 128 / 32), 256, 0, stream>>>(W1, w1t, D_IN, D_HID);
    transpose_cvt_kernel<<<dim3(128 / 32, 1024 / 32), 256, 0, stream>>>(W2, w2t, D_HID, D_OUT);

    // gather (atomic-free), writes bf16 h
    gather_kernel<<<(N_NODES + 3) / 4, 256, 0, stream>>>(feat, edge_feat, src, eid, off, hbf);

    // fused MFMA MLP
    mlp_mfma_kernel<<<(N_NODES + 63) / 64, 256, 0, stream>>>(hbf, w1t, b1, w2t, b2, out);
}